// Round 4
// baseline (524.842 us; speedup 1.0000x reference)
//
#include <hip/hip_runtime.h>
#include <hip/hip_bf16.h>

// Problem constants
#define BB 4
#define NN 50000
#define DIN 128
#define DOUT 128
#define EE 800000
#define TOTROWS (BB * NN)   // 200000

typedef unsigned short u16;
typedef unsigned int u32;

using shortx8 = __attribute__((ext_vector_type(8))) short;
using ushortx4 = __attribute__((ext_vector_type(4))) unsigned short;
using ushortx8 = __attribute__((ext_vector_type(8))) unsigned short;
using floatx4 = __attribute__((ext_vector_type(4))) float;

__device__ __forceinline__ float b2f(u16 u) {
    u32 x = ((u32)u) << 16;
    float f;
    __builtin_memcpy(&f, &x, 4);
    return f;
}

__device__ __forceinline__ u16 f2b(float f) {
    u32 x;
    __builtin_memcpy(&x, &f, 4);
    u32 r = x + 0x7fffu + ((x >> 16) & 1u);   // RNE
    return (u16)(r >> 16);
}

// ---------------------------------------------------------------------------
// K0: dtype detector. For each float input, sample even-indexed u16s.
// bf16-stored  -> samples are bf16 values, exponent field in ~[90,141].
// fp32-stored  -> samples are low mantissa halves, exponent field uniform.
// flags[i] = 1 if fp32-stored, 0 if bf16-stored.
// ---------------------------------------------------------------------------
__global__ __launch_bounds__(256)
void k_detect(const u16* __restrict__ X, const u16* __restrict__ W,
              const u16* __restrict__ Bs, const u16* __restrict__ V,
              int nx, int nw, int nb, int nv, int* __restrict__ flags) {
    __shared__ int cnt[4];
    const int t = threadIdx.x;
    const int w = t >> 6;
    const int l = t & 63;
    if (t < 4) cnt[t] = 0;
    __syncthreads();
    const u16* p = (w == 0) ? X : (w == 1) ? W : (w == 2) ? Bs : V;
    const int n  = (w == 0) ? nx : (w == 1) ? nw : (w == 2) ? nb : nv;
    int bad = 0;
    for (int k = 0; k < 4; ++k) {
        // even u16 index within the smaller (bf16) interpretation [0, n)
        unsigned idx = 2u * (unsigned)(((unsigned long long)(l * 4 + k) *
                                        (unsigned)(n >> 1)) >> 8);
        u16 s = p[idx];
        unsigned e = (s >> 7) & 0xFF;
        bool ok = ((s & 0x7FFF) == 0) || (e >= 90 && e <= 141);
        bad += ok ? 0 : 1;
    }
    atomicAdd(&cnt[w], bad);
    __syncthreads();
    if (l == 0) flags[w] = (cnt[w] >= 77) ? 1 : 0;   // >=30% implausible
}

// ---------------------------------------------------------------------------
// K1: sup[(n*B + b)*128 + f] = bf16( X[b*N+n,:] @ W )   fp32-accum MFMA.
// 128 rows x 128 cols per block; dual-dtype loads per flags.
// ---------------------------------------------------------------------------
__global__ __launch_bounds__(256, 2)
void k_gemm(const void* __restrict__ Xv, const void* __restrict__ Wv,
            const int* __restrict__ flags, u16* __restrict__ sup) {
    __shared__ u16 lA[128 * 128];   // 32 KB bf16, row-major

    const int xf32 = flags[0];
    const int wf32 = flags[1];
    const float* Xf  = (const float*)Xv;
    const u16*   X16 = (const u16*)Xv;
    const float* Wf  = (const float*)Wv;
    const u16*   W16 = (const u16*)Wv;

    const int tid = threadIdx.x;
    const int wid = tid >> 6;
    const int l   = tid & 63;
    const long rowBase = (long)blockIdx.x * 128;

    // Stage + (maybe convert) X tile: 16384 elems, 4 per thread per iter.
#pragma unroll
    for (int i = 0; i < 16; ++i) {
        int elem = i * 1024 + tid * 4;       // == row*128 + col
        int row = elem >> 7;
        int col = elem & 127;
        long gRow = rowBase + row;
        ushortx4 w4;
        if (gRow < TOTROWS) {
            if (xf32) {
                float4 v = *(const float4*)(Xf + gRow * DIN + col);
                w4[0] = f2b(v.x); w4[1] = f2b(v.y);
                w4[2] = f2b(v.z); w4[3] = f2b(v.w);
            } else {
                w4 = *(const ushortx4*)(X16 + gRow * DIN + col);
            }
        } else {
            w4 = (ushortx4){0, 0, 0, 0};
        }
        *(ushortx4*)&lA[elem] = w4;
    }

    const int wx = wid & 1;        // col half (0/1)
    const int wy = wid >> 1;       // row half (0/1)
    const int q8 = (l >> 4) * 8;   // k sub-offset for A/B frags
    const int lm = l & 15;

    // W fragments -> registers (16 frags: 4 n-tiles x 4 k-chunks)
    shortx8 bf[16];
    for (int nt = 0; nt < 4; ++nt) {
        const int F = wx * 64 + nt * 16 + lm;
        for (int c = 0; c < 4; ++c) {
#pragma unroll
            for (int j = 0; j < 8; ++j) {
                size_t idx = (size_t)(32 * c + q8 + j) * DOUT + F;
                bf[nt * 4 + c][j] = wf32 ? (short)f2b(Wf[idx]) : (short)W16[idx];
            }
        }
    }

    floatx4 acc[4][4];
#pragma unroll
    for (int mt = 0; mt < 4; ++mt)
#pragma unroll
        for (int nt = 0; nt < 4; ++nt)
            acc[mt][nt] = (floatx4){0.f, 0.f, 0.f, 0.f};

    __syncthreads();

    for (int c = 0; c < 4; ++c) {
        shortx8 af[4];
#pragma unroll
        for (int mt = 0; mt < 4; ++mt) {
            const size_t idx = (size_t)(wy * 64 + mt * 16 + lm) * 128 + 32 * c + q8;
            af[mt] = *(const shortx8*)&lA[idx];
        }
#pragma unroll
        for (int mt = 0; mt < 4; ++mt)
#pragma unroll
            for (int nt = 0; nt < 4; ++nt)
                acc[mt][nt] = __builtin_amdgcn_mfma_f32_16x16x32_bf16(
                    af[mt], bf[nt * 4 + c], acc[mt][nt], 0, 0, 0);
    }

    // Epilogue: C/D layout col = l&15, row = (l>>4)*4 + reg (m89-verified)
#pragma unroll
    for (int mt = 0; mt < 4; ++mt) {
#pragma unroll
        for (int reg = 0; reg < 4; ++reg) {
            long R = rowBase + wy * 64 + mt * 16 + (l >> 4) * 4 + reg;
            if (R < TOTROWS) {
                int b = (int)(R / NN);
                int n = (int)(R % NN);
                size_t outRow = ((size_t)n * BB + b) * DOUT;
#pragma unroll
                for (int nt = 0; nt < 4; ++nt) {
                    int F = wx * 64 + nt * 16 + lm;
                    sup[outRow + F] = f2b(acc[mt][nt][reg]);
                }
            }
        }
    }
}

// ---------------------------------------------------------------------------
// CSR build
// ---------------------------------------------------------------------------
__global__ __launch_bounds__(256)
void k_hist(const int* __restrict__ rows, int* __restrict__ deg) {
    int e = blockIdx.x * 256 + threadIdx.x;
    if (e < EE) atomicAdd(&deg[rows[e]], 1);
}

#define CHUNK 1024
#define NCHUNK ((NN + CHUNK - 1) / CHUNK)   // 49

__global__ __launch_bounds__(256)
void k_scan_reduce(const int* __restrict__ deg, int* __restrict__ bsum) {
    __shared__ int sh[256];
    int t = threadIdx.x, blk = blockIdx.x;
    int base = blk * CHUNK + t * 4;
    int s = 0;
#pragma unroll
    for (int i = 0; i < 4; ++i) {
        int idx = base + i;
        if (idx < NN) s += deg[idx];
    }
    sh[t] = s;
    __syncthreads();
    for (int d = 128; d > 0; d >>= 1) {
        if (t < d) sh[t] += sh[t + d];
        __syncthreads();
    }
    if (t == 0) bsum[blk] = sh[0];
}

__global__ __launch_bounds__(64)
void k_scan_base(const int* __restrict__ bsum, int* __restrict__ bbase,
                 int* __restrict__ off) {
    if (threadIdx.x == 0) {
        int run = 0;
        for (int i = 0; i < NCHUNK; ++i) {
            bbase[i] = run;
            run += bsum[i];
        }
        off[NN] = run;   // == E
    }
}

__global__ __launch_bounds__(256)
void k_scan_chunk(const int* __restrict__ deg, const int* __restrict__ bbase,
                  int* __restrict__ off) {
    __shared__ int sh[256];
    int t = threadIdx.x;
    int blk = blockIdx.x;
    int base = blk * CHUNK + t * 4;
    int v[4];
    int tsum = 0;
#pragma unroll
    for (int i = 0; i < 4; ++i) {
        int idx = base + i;
        v[i] = (idx < NN) ? deg[idx] : 0;
        tsum += v[i];
    }
    sh[t] = tsum;
    __syncthreads();
    for (int d = 1; d < 256; d <<= 1) {
        int x = (t >= d) ? sh[t - d] : 0;
        __syncthreads();
        sh[t] += x;
        __syncthreads();
    }
    int run = sh[t] - tsum + bbase[blk];   // exclusive prefix + chunk base
#pragma unroll
    for (int i = 0; i < 4; ++i) {
        int idx = base + i;
        if (idx < NN) off[idx] = run;
        run += v[i];
    }
}

__global__ __launch_bounds__(256)
void k_scatter(const int* __restrict__ rows, const int* __restrict__ cols,
               const void* __restrict__ valsv, const int* __restrict__ flags,
               const int* __restrict__ off, int* __restrict__ cur,
               int* __restrict__ ecol, float* __restrict__ eval) {
    int e = blockIdx.x * 256 + threadIdx.x;
    if (e < EE) {
        int vf32 = flags[3];
        float v = vf32 ? ((const float*)valsv)[e] : b2f(((const u16*)valsv)[e]);
        int r = rows[e];
        int p = off[r] + atomicAdd(&cur[r], 1);
        ecol[p] = cols[e];
        eval[p] = v;
    }
}

// ---------------------------------------------------------------------------
// K8: aggregation. One wave per node; lane covers (b = l>>4, f = (l&15)*8+t).
// out[b][n][f] = relu( sum_e val_e * sup[(col_e*B + b)*128 + f] + bias[f] )
// Output is FP32.
// ---------------------------------------------------------------------------
__global__ __launch_bounds__(256)
void k_agg(const u16* __restrict__ sup, const int* __restrict__ off,
           const int* __restrict__ ecol, const float* __restrict__ eval,
           const void* __restrict__ biasv, const int* __restrict__ flags,
           float* __restrict__ out) {
    const int wid = threadIdx.x >> 6;
    const int l   = threadIdx.x & 63;
    const int n = blockIdx.x * 4 + wid;
    if (n >= NN) return;

    const int p0 = off[n];
    const int p1 = off[n + 1];

    float acc[8] = {0.f, 0.f, 0.f, 0.f, 0.f, 0.f, 0.f, 0.f};
    const int b  = l >> 4;
    const int f0 = (l & 15) * 8;

    for (int p = p0; p < p1; ++p) {
        int c = ecol[p];
        float v = eval[p];
        // l*8 == (l>>4)*128 + (l&15)*8  -> [n][b][f] interleaved gather
        ushortx8 s = *(const ushortx8*)(sup + (size_t)c * 512 + l * 8);
#pragma unroll
        for (int t = 0; t < 8; ++t) acc[t] += v * b2f(s[t]);
    }

    float bb[8];
    if (flags[2]) {
        float4 bv1 = *(const float4*)((const float*)biasv + f0);
        float4 bv2 = *(const float4*)((const float*)biasv + f0 + 4);
        bb[0] = bv1.x; bb[1] = bv1.y; bb[2] = bv1.z; bb[3] = bv1.w;
        bb[4] = bv2.x; bb[5] = bv2.y; bb[6] = bv2.z; bb[7] = bv2.w;
    } else {
        ushortx8 bv = *(const ushortx8*)((const u16*)biasv + f0);
#pragma unroll
        for (int t = 0; t < 8; ++t) bb[t] = b2f(bv[t]);
    }

    float r[8];
#pragma unroll
    for (int t = 0; t < 8; ++t) r[t] = fmaxf(acc[t] + bb[t], 0.f);

    float* op = out + ((size_t)b * NN + n) * DOUT + f0;
    *(float4*)op       = (float4){r[0], r[1], r[2], r[3]};
    *(float4*)(op + 4) = (float4){r[4], r[5], r[6], r[7]};
}

// ---------------------------------------------------------------------------
extern "C" void kernel_launch(void* const* d_in, const int* in_sizes, int n_in,
                              void* d_out, int out_size, void* d_ws, size_t ws_size,
                              hipStream_t stream) {
    const void* X    = d_in[0];              // [B,N,DIN]  fp32 (detector-verified)
    const void* W    = d_in[1];              // [DIN,DOUT]
    const void* bias = d_in[2];              // [DOUT]
    const void* vals = d_in[3];              // [E]
    const int* rows  = (const int*)d_in[4];  // [E] int32
    const int* cols  = (const int*)d_in[5];  // [E] int32
    float* out = (float*)d_out;              // [B,N,DOUT] fp32

    char* base = (char*)d_ws;
    size_t o = 0;
    int* flags = (int*)(base + o); o += 64;              // dtype flags
    int* deg = (int*)(base + o); o += (size_t)NN * 4;
    int* cur = (int*)(base + o); o += (size_t)NN * 4;    // deg+cur contiguous
    o = (o + 255) & ~(size_t)255;
    int* bsum  = (int*)(base + o); o += 64 * 4;
    int* bbase = (int*)(base + o); o += 64 * 4;
    o = (o + 255) & ~(size_t)255;
    int* off = (int*)(base + o); o += (size_t)(NN + 1) * 4;
    o = (o + 255) & ~(size_t)255;
    int* ecol = (int*)(base + o); o += (size_t)EE * 4;
    float* eval = (float*)(base + o); o += (size_t)EE * 4;
    o = (o + 255) & ~(size_t)255;
    u16* sup = (u16*)(base + o); o += (size_t)BB * NN * DOUT * 2;
    (void)ws_size;

    hipMemsetAsync(deg, 0, (size_t)2 * NN * 4, stream);  // deg + cur

    k_detect<<<1, 256, 0, stream>>>((const u16*)X, (const u16*)W,
                                    (const u16*)bias, (const u16*)vals,
                                    in_sizes[0], in_sizes[1], in_sizes[2],
                                    in_sizes[3], flags);
    k_gemm<<<(TOTROWS + 127) / 128, 256, 0, stream>>>(X, W, flags, sup);
    k_hist<<<(EE + 255) / 256, 256, 0, stream>>>(rows, deg);
    k_scan_reduce<<<NCHUNK, 256, 0, stream>>>(deg, bsum);
    k_scan_base<<<1, 64, 0, stream>>>(bsum, bbase, off);
    k_scan_chunk<<<NCHUNK, 256, 0, stream>>>(deg, bbase, off);
    k_scatter<<<(EE + 255) / 256, 256, 0, stream>>>(rows, cols, vals, flags,
                                                    off, cur, ecol, eval);
    k_agg<<<(NN + 3) / 4, 256, 0, stream>>>(sup, off, ecol, eval, bias, flags,
                                            out);
}

// Round 5
// 431.065 us; speedup vs baseline: 1.2175x; 1.2175x over previous
//
#include <hip/hip_runtime.h>
#include <hip/hip_bf16.h>

// Problem constants
#define BB 4
#define NN 50000
#define DIN 128
#define DOUT 128
#define EE 800000
#define TOTROWS (BB * NN)   // 200000
#define LDA 136             // padded LDS row stride (u16): 272B = 17*16B

typedef unsigned short u16;
typedef unsigned int u32;

using shortx8 = __attribute__((ext_vector_type(8))) short;
using ushortx4 = __attribute__((ext_vector_type(4))) unsigned short;
using ushortx8 = __attribute__((ext_vector_type(8))) unsigned short;
using floatx4 = __attribute__((ext_vector_type(4))) float;

__device__ __forceinline__ float b2f(u16 u) {
    u32 x = ((u32)u) << 16;
    float f;
    __builtin_memcpy(&f, &x, 4);
    return f;
}

__device__ __forceinline__ u16 f2b(float f) {
    u32 x;
    __builtin_memcpy(&x, &f, 4);
    u32 r = x + 0x7fffu + ((x >> 16) & 1u);   // RNE
    return (u16)(r >> 16);
}

// ---------------------------------------------------------------------------
// K0: dtype detector (bf16-stored vs fp32-stored float inputs).
// flags[i] = 1 if fp32-stored, 0 if bf16-stored.
// ---------------------------------------------------------------------------
__global__ __launch_bounds__(256)
void k_detect(const u16* __restrict__ X, const u16* __restrict__ W,
              const u16* __restrict__ Bs, const u16* __restrict__ V,
              int nx, int nw, int nb, int nv, int* __restrict__ flags) {
    __shared__ int cnt[4];
    const int t = threadIdx.x;
    const int w = t >> 6;
    const int l = t & 63;
    if (t < 4) cnt[t] = 0;
    __syncthreads();
    const u16* p = (w == 0) ? X : (w == 1) ? W : (w == 2) ? Bs : V;
    const int n  = (w == 0) ? nx : (w == 1) ? nw : (w == 2) ? nb : nv;
    int bad = 0;
    for (int k = 0; k < 4; ++k) {
        unsigned idx = 2u * (unsigned)(((unsigned long long)(l * 4 + k) *
                                        (unsigned)(n >> 1)) >> 8);
        u16 s = p[idx];
        unsigned e = (s >> 7) & 0xFF;
        bool ok = ((s & 0x7FFF) == 0) || (e >= 90 && e <= 141);
        bad += ok ? 0 : 1;
    }
    atomicAdd(&cnt[w], bad);
    __syncthreads();
    if (l == 0) flags[w] = (cnt[w] >= 77) ? 1 : 0;   // >=30% implausible
}

// ---------------------------------------------------------------------------
// K0b: Wt[f*128 + k] = bf16(W[k*128 + f])  (transpose + convert, 16K elems)
// So GEMM B-fragments become contiguous 16B vector loads.
// ---------------------------------------------------------------------------
__global__ __launch_bounds__(256)
void k_prep(const void* __restrict__ Wv, const int* __restrict__ flags,
            u16* __restrict__ Wt) {
    int t = blockIdx.x * 256 + threadIdx.x;
    if (t < DIN * DOUT) {
        int f = t >> 7, k = t & 127;
        size_t src = (size_t)k * DOUT + f;
        Wt[t] = flags[1] ? f2b(((const float*)Wv)[src]) : ((const u16*)Wv)[src];
    }
}

// ---------------------------------------------------------------------------
// K1: sup[(n*B + b)*128 + f] = bf16( X[b*N+n,:] @ W )   fp32-accum MFMA.
// 128x128 tile/block; padded LDS (no bank conflicts); vector W-frag loads.
// ---------------------------------------------------------------------------
__global__ __launch_bounds__(256, 3)
void k_gemm(const void* __restrict__ Xv, const u16* __restrict__ Wt,
            const int* __restrict__ flags, u16* __restrict__ sup) {
    __shared__ u16 lA[128 * LDA];   // 34 KB

    const int xf32 = flags[0];
    const int tid = threadIdx.x;
    const int wid = tid >> 6;
    const int l   = tid & 63;
    const long rowBase = (long)blockIdx.x * 128;

    // Stage + (maybe convert) X tile into padded LDS.
    if (xf32) {
        const float* Xf = (const float*)Xv;
#pragma unroll
        for (int i = 0; i < 16; ++i) {
            int elem = i * 1024 + tid * 4;   // row*128 + col
            int row = elem >> 7, col = elem & 127;
            long gRow = rowBase + row;
            ushortx4 w4 = (ushortx4){0, 0, 0, 0};
            if (gRow < TOTROWS) {
                float4 v = *(const float4*)(Xf + gRow * DIN + col);
                w4[0] = f2b(v.x); w4[1] = f2b(v.y);
                w4[2] = f2b(v.z); w4[3] = f2b(v.w);
            }
            *(ushortx4*)&lA[row * LDA + col] = w4;   // 8B store
        }
    } else {
        const u16* X16 = (const u16*)Xv;
#pragma unroll
        for (int i = 0; i < 8; ++i) {
            int elem = i * 2048 + tid * 8;
            int row = elem >> 7, col = elem & 127;
            long gRow = rowBase + row;
            ushortx8 w8 = (ushortx8){0, 0, 0, 0, 0, 0, 0, 0};
            if (gRow < TOTROWS)
                w8 = *(const ushortx8*)(X16 + gRow * DIN + col);
            *(ushortx8*)&lA[row * LDA + col] = w8;   // 16B store (272B stride ok)
        }
    }

    const int wx = wid & 1;        // col half
    const int wy = wid >> 1;       // row half
    const int q8 = (l >> 4) * 8;   // k sub-offset
    const int lm = l & 15;

    // All 16 W fragments via 16B vector loads from Wt (L2-hot, 32 KB).
    shortx8 bf[16];
#pragma unroll
    for (int nt = 0; nt < 4; ++nt) {
        const size_t Frow = (size_t)(wx * 64 + nt * 16 + lm) * DIN;
#pragma unroll
        for (int c = 0; c < 4; ++c)
            bf[nt * 4 + c] = *(const shortx8*)(Wt + Frow + 32 * c + q8);
    }

    floatx4 acc[4][4];
#pragma unroll
    for (int mt = 0; mt < 4; ++mt)
#pragma unroll
        for (int nt = 0; nt < 4; ++nt)
            acc[mt][nt] = (floatx4){0.f, 0.f, 0.f, 0.f};

    __syncthreads();

    for (int c = 0; c < 4; ++c) {
        shortx8 af[4];
#pragma unroll
        for (int mt = 0; mt < 4; ++mt)
            af[mt] = *(const shortx8*)
                &lA[(size_t)(wy * 64 + mt * 16 + lm) * LDA + 32 * c + q8];
#pragma unroll
        for (int mt = 0; mt < 4; ++mt)
#pragma unroll
            for (int nt = 0; nt < 4; ++nt)
                acc[mt][nt] = __builtin_amdgcn_mfma_f32_16x16x32_bf16(
                    af[mt], bf[nt * 4 + c], acc[mt][nt], 0, 0, 0);
    }

    // Epilogue: C/D layout col = l&15, row = (l>>4)*4 + reg
#pragma unroll
    for (int mt = 0; mt < 4; ++mt) {
#pragma unroll
        for (int reg = 0; reg < 4; ++reg) {
            long R = rowBase + wy * 64 + mt * 16 + (l >> 4) * 4 + reg;
            if (R < TOTROWS) {
                int b = (int)(R / NN);
                int n = (int)(R % NN);
                size_t outRow = ((size_t)n * BB + b) * DOUT;
#pragma unroll
                for (int nt = 0; nt < 4; ++nt) {
                    int F = wx * 64 + nt * 16 + lm;
                    sup[outRow + F] = f2b(acc[mt][nt][reg]);
                }
            }
        }
    }
}

// ---------------------------------------------------------------------------
// CSR build
// ---------------------------------------------------------------------------
__global__ __launch_bounds__(256)
void k_hist(const int* __restrict__ rows, int* __restrict__ deg) {
    int e = blockIdx.x * 256 + threadIdx.x;
    if (e < EE) atomicAdd(&deg[rows[e]], 1);
}

#define CHUNK 1024
#define NCHUNK ((NN + CHUNK - 1) / CHUNK)   // 49

__global__ __launch_bounds__(256)
void k_scan_reduce(const int* __restrict__ deg, int* __restrict__ bsum) {
    __shared__ int sh[256];
    int t = threadIdx.x, blk = blockIdx.x;
    int base = blk * CHUNK + t * 4;
    int s = 0;
#pragma unroll
    for (int i = 0; i < 4; ++i) {
        int idx = base + i;
        if (idx < NN) s += deg[idx];
    }
    sh[t] = s;
    __syncthreads();
    for (int d = 128; d > 0; d >>= 1) {
        if (t < d) sh[t] += sh[t + d];
        __syncthreads();
    }
    if (t == 0) bsum[blk] = sh[0];
}

__global__ __launch_bounds__(64)
void k_scan_base(const int* __restrict__ bsum, int* __restrict__ bbase,
                 int* __restrict__ off) {
    if (threadIdx.x == 0) {
        int run = 0;
        for (int i = 0; i < NCHUNK; ++i) {
            bbase[i] = run;
            run += bsum[i];
        }
        off[NN] = run;   // == E
    }
}

__global__ __launch_bounds__(256)
void k_scan_chunk(const int* __restrict__ deg, const int* __restrict__ bbase,
                  int* __restrict__ off) {
    __shared__ int sh[256];
    int t = threadIdx.x;
    int blk = blockIdx.x;
    int base = blk * CHUNK + t * 4;
    int v[4];
    int tsum = 0;
#pragma unroll
    for (int i = 0; i < 4; ++i) {
        int idx = base + i;
        v[i] = (idx < NN) ? deg[idx] : 0;
        tsum += v[i];
    }
    sh[t] = tsum;
    __syncthreads();
    for (int d = 1; d < 256; d <<= 1) {
        int x = (t >= d) ? sh[t - d] : 0;
        __syncthreads();
        sh[t] += x;
        __syncthreads();
    }
    int run = sh[t] - tsum + bbase[blk];
#pragma unroll
    for (int i = 0; i < 4; ++i) {
        int idx = base + i;
        if (idx < NN) off[idx] = run;
        run += v[i];
    }
}

__global__ __launch_bounds__(256)
void k_scatter(const int* __restrict__ rows, const int* __restrict__ cols,
               const void* __restrict__ valsv, const int* __restrict__ flags,
               const int* __restrict__ off, int* __restrict__ cur,
               int* __restrict__ ecol, float* __restrict__ eval) {
    int e = blockIdx.x * 256 + threadIdx.x;
    if (e < EE) {
        int vf32 = flags[3];
        float v = vf32 ? ((const float*)valsv)[e] : b2f(((const u16*)valsv)[e]);
        int r = rows[e];
        int p = off[r] + atomicAdd(&cur[r], 1);
        ecol[p] = cols[e];
        eval[p] = v;
    }
}

// ---------------------------------------------------------------------------
// K8: aggregation. One wave per node; lane covers (b = l>>4, f = (l&15)*8+t).
// out fp32. Edge loop unrolled x2 for memory-level parallelism.
// ---------------------------------------------------------------------------
__global__ __launch_bounds__(256)
void k_agg(const u16* __restrict__ sup, const int* __restrict__ off,
           const int* __restrict__ ecol, const float* __restrict__ eval,
           const void* __restrict__ biasv, const int* __restrict__ flags,
           float* __restrict__ out) {
    const int wid = threadIdx.x >> 6;
    const int l   = threadIdx.x & 63;
    const int n = blockIdx.x * 4 + wid;
    if (n >= NN) return;

    const int p0 = off[n];
    const int p1 = off[n + 1];

    float acc[8] = {0.f, 0.f, 0.f, 0.f, 0.f, 0.f, 0.f, 0.f};
    const int b  = l >> 4;
    const int f0 = (l & 15) * 8;
    const int lofs = l * 8;   // == b*128 + f0 in [n][b][f] layout

    int p = p0;
    for (; p + 2 <= p1; p += 2) {
        int c0 = ecol[p], c1 = ecol[p + 1];
        float v0 = eval[p], v1 = eval[p + 1];
        ushortx8 s0 = *(const ushortx8*)(sup + (size_t)c0 * 512 + lofs);
        ushortx8 s1 = *(const ushortx8*)(sup + (size_t)c1 * 512 + lofs);
#pragma unroll
        for (int t = 0; t < 8; ++t) acc[t] += v0 * b2f(s0[t]);
#pragma unroll
        for (int t = 0; t < 8; ++t) acc[t] += v1 * b2f(s1[t]);
    }
    if (p < p1) {
        int c = ecol[p];
        float v = eval[p];
        ushortx8 s = *(const ushortx8*)(sup + (size_t)c * 512 + lofs);
#pragma unroll
        for (int t = 0; t < 8; ++t) acc[t] += v * b2f(s[t]);
    }

    float bb[8];
    if (flags[2]) {
        float4 bv1 = *(const float4*)((const float*)biasv + f0);
        float4 bv2 = *(const float4*)((const float*)biasv + f0 + 4);
        bb[0] = bv1.x; bb[1] = bv1.y; bb[2] = bv1.z; bb[3] = bv1.w;
        bb[4] = bv2.x; bb[5] = bv2.y; bb[6] = bv2.z; bb[7] = bv2.w;
    } else {
        ushortx8 bv = *(const ushortx8*)((const u16*)biasv + f0);
#pragma unroll
        for (int t = 0; t < 8; ++t) bb[t] = b2f(bv[t]);
    }

    float r[8];
#pragma unroll
    for (int t = 0; t < 8; ++t) r[t] = fmaxf(acc[t] + bb[t], 0.f);

    float* op = out + ((size_t)b * NN + n) * DOUT + f0;
    *(float4*)op       = (float4){r[0], r[1], r[2], r[3]};
    *(float4*)(op + 4) = (float4){r[4], r[5], r[6], r[7]};
}

// ---------------------------------------------------------------------------
extern "C" void kernel_launch(void* const* d_in, const int* in_sizes, int n_in,
                              void* d_out, int out_size, void* d_ws, size_t ws_size,
                              hipStream_t stream) {
    const void* X    = d_in[0];
    const void* W    = d_in[1];
    const void* bias = d_in[2];
    const void* vals = d_in[3];
    const int* rows  = (const int*)d_in[4];
    const int* cols  = (const int*)d_in[5];
    float* out = (float*)d_out;

    char* base = (char*)d_ws;
    size_t o = 0;
    int* flags = (int*)(base + o); o += 64;
    int* deg = (int*)(base + o); o += (size_t)NN * 4;
    int* cur = (int*)(base + o); o += (size_t)NN * 4;    // deg+cur contiguous
    o = (o + 255) & ~(size_t)255;
    int* bsum  = (int*)(base + o); o += 64 * 4;
    int* bbase = (int*)(base + o); o += 64 * 4;
    o = (o + 255) & ~(size_t)255;
    u16* Wt = (u16*)(base + o); o += (size_t)DIN * DOUT * 2;
    o = (o + 255) & ~(size_t)255;
    int* off = (int*)(base + o); o += (size_t)(NN + 1) * 4;
    o = (o + 255) & ~(size_t)255;
    int* ecol = (int*)(base + o); o += (size_t)EE * 4;
    float* eval = (float*)(base + o); o += (size_t)EE * 4;
    o = (o + 255) & ~(size_t)255;
    u16* sup = (u16*)(base + o); o += (size_t)BB * NN * DOUT * 2;
    (void)ws_size;

    hipMemsetAsync(deg, 0, (size_t)2 * NN * 4, stream);  // deg + cur

    k_detect<<<1, 256, 0, stream>>>((const u16*)X, (const u16*)W,
                                    (const u16*)bias, (const u16*)vals,
                                    in_sizes[0], in_sizes[1], in_sizes[2],
                                    in_sizes[3], flags);
    k_prep<<<64, 256, 0, stream>>>(W, flags, Wt);
    k_gemm<<<(TOTROWS + 127) / 128, 256, 0, stream>>>(X, Wt, flags, sup);
    k_hist<<<(EE + 255) / 256, 256, 0, stream>>>(rows, deg);
    k_scan_reduce<<<NCHUNK, 256, 0, stream>>>(deg, bsum);
    k_scan_base<<<1, 64, 0, stream>>>(bsum, bbase, off);
    k_scan_chunk<<<NCHUNK, 256, 0, stream>>>(deg, bbase, off);
    k_scatter<<<(EE + 255) / 256, 256, 0, stream>>>(rows, cols, vals, flags,
                                                    off, cur, ecol, eval);
    k_agg<<<(NN + 3) / 4, 256, 0, stream>>>(sup, off, ecol, eval, bias, flags,
                                            out);
}

// Round 6
// 425.299 us; speedup vs baseline: 1.2341x; 1.0136x over previous
//
#include <hip/hip_runtime.h>
#include <hip/hip_bf16.h>

// Problem constants
#define BB 4
#define NN 50000
#define DIN 128
#define DOUT 128
#define EE 800000
#define TOTROWS (BB * NN)   // 200000
#define LDA 136             // padded LDS row stride (u16): 272B = 17*16B

typedef unsigned short u16;
typedef unsigned int u32;

using shortx8 = __attribute__((ext_vector_type(8))) short;
using ushortx4 = __attribute__((ext_vector_type(4))) unsigned short;
using ushortx8 = __attribute__((ext_vector_type(8))) unsigned short;
using floatx4 = __attribute__((ext_vector_type(4))) float;

__device__ __forceinline__ float b2f(u16 u) {
    u32 x = ((u32)u) << 16;
    float f;
    __builtin_memcpy(&f, &x, 4);
    return f;
}

__device__ __forceinline__ u16 f2b(float f) {
    u32 x;
    __builtin_memcpy(&x, &f, 4);
    u32 r = x + 0x7fffu + ((x >> 16) & 1u);   // RNE
    return (u16)(r >> 16);
}

// ---------------------------------------------------------------------------
// K0: dtype detector (bf16-stored vs fp32-stored float inputs).
// flags[i] = 1 if fp32-stored, 0 if bf16-stored.
// ---------------------------------------------------------------------------
__global__ __launch_bounds__(256)
void k_detect(const u16* __restrict__ X, const u16* __restrict__ W,
              const u16* __restrict__ Bs, const u16* __restrict__ V,
              int nx, int nw, int nb, int nv, int* __restrict__ flags) {
    __shared__ int cnt[4];
    const int t = threadIdx.x;
    const int w = t >> 6;
    const int l = t & 63;
    if (t < 4) cnt[t] = 0;
    __syncthreads();
    const u16* p = (w == 0) ? X : (w == 1) ? W : (w == 2) ? Bs : V;
    const int n  = (w == 0) ? nx : (w == 1) ? nw : (w == 2) ? nb : nv;
    int bad = 0;
    for (int k = 0; k < 4; ++k) {
        unsigned idx = 2u * (unsigned)(((unsigned long long)(l * 4 + k) *
                                        (unsigned)(n >> 1)) >> 8);
        u16 s = p[idx];
        unsigned e = (s >> 7) & 0xFF;
        bool ok = ((s & 0x7FFF) == 0) || (e >= 90 && e <= 141);
        bad += ok ? 0 : 1;
    }
    atomicAdd(&cnt[w], bad);
    __syncthreads();
    if (l == 0) flags[w] = (cnt[w] >= 77) ? 1 : 0;   // >=30% implausible
}

// ---------------------------------------------------------------------------
// K0b: Wt[f*128 + k] = bf16(W[k*128 + f])  (transpose + convert)
// ---------------------------------------------------------------------------
__global__ __launch_bounds__(256)
void k_prep(const void* __restrict__ Wv, const int* __restrict__ flags,
            u16* __restrict__ Wt) {
    int t = blockIdx.x * 256 + threadIdx.x;
    if (t < DIN * DOUT) {
        int f = t >> 7, k = t & 127;
        size_t src = (size_t)k * DOUT + f;
        Wt[t] = flags[1] ? f2b(((const float*)Wv)[src]) : ((const u16*)Wv)[src];
    }
}

// ---------------------------------------------------------------------------
// K1: sup[(n*B + b)*128 + f] = bf16( X[b*N+n,:] @ W )   fp32-accum MFMA.
// 128x128 tile/block; padded LDS; epilogue via LDS for coalesced 16B stores.
// ---------------------------------------------------------------------------
__global__ __launch_bounds__(256, 3)
void k_gemm(const void* __restrict__ Xv, const u16* __restrict__ Wt,
            const int* __restrict__ flags, u16* __restrict__ sup) {
    __shared__ u16 lA[128 * LDA];   // 34 KB

    const int xf32 = flags[0];
    const int tid = threadIdx.x;
    const int wid = tid >> 6;
    const int l   = tid & 63;
    const long rowBase = (long)blockIdx.x * 128;

    // Stage + (maybe convert) X tile into padded LDS.
    if (xf32) {
        const float* Xf = (const float*)Xv;
#pragma unroll
        for (int i = 0; i < 16; ++i) {
            int elem = i * 1024 + tid * 4;   // row*128 + col
            int row = elem >> 7, col = elem & 127;
            long gRow = rowBase + row;
            ushortx4 w4 = (ushortx4){0, 0, 0, 0};
            if (gRow < TOTROWS) {
                float4 v = *(const float4*)(Xf + gRow * DIN + col);
                w4[0] = f2b(v.x); w4[1] = f2b(v.y);
                w4[2] = f2b(v.z); w4[3] = f2b(v.w);
            }
            *(ushortx4*)&lA[row * LDA + col] = w4;
        }
    } else {
        const u16* X16 = (const u16*)Xv;
#pragma unroll
        for (int i = 0; i < 8; ++i) {
            int elem = i * 2048 + tid * 8;
            int row = elem >> 7, col = elem & 127;
            long gRow = rowBase + row;
            ushortx8 w8 = (ushortx8){0, 0, 0, 0, 0, 0, 0, 0};
            if (gRow < TOTROWS)
                w8 = *(const ushortx8*)(X16 + gRow * DIN + col);
            *(ushortx8*)&lA[row * LDA + col] = w8;
        }
    }

    const int wx = wid & 1;        // col half
    const int wy = wid >> 1;       // row half
    const int q8 = (l >> 4) * 8;   // k sub-offset
    const int lm = l & 15;

    // W fragments via 16B vector loads from Wt (L1/L2-hot, 32 KB).
    shortx8 bf[16];
#pragma unroll
    for (int nt = 0; nt < 4; ++nt) {
        const size_t Frow = (size_t)(wx * 64 + nt * 16 + lm) * DIN;
#pragma unroll
        for (int c = 0; c < 4; ++c)
            bf[nt * 4 + c] = *(const shortx8*)(Wt + Frow + 32 * c + q8);
    }

    floatx4 acc[4][4];
#pragma unroll
    for (int mt = 0; mt < 4; ++mt)
#pragma unroll
        for (int nt = 0; nt < 4; ++nt)
            acc[mt][nt] = (floatx4){0.f, 0.f, 0.f, 0.f};

    __syncthreads();

    for (int c = 0; c < 4; ++c) {
        shortx8 af[4];
#pragma unroll
        for (int mt = 0; mt < 4; ++mt)
            af[mt] = *(const shortx8*)
                &lA[(size_t)(wy * 64 + mt * 16 + lm) * LDA + 32 * c + q8];
#pragma unroll
        for (int mt = 0; mt < 4; ++mt)
#pragma unroll
            for (int nt = 0; nt < 4; ++nt)
                acc[mt][nt] = __builtin_amdgcn_mfma_f32_16x16x32_bf16(
                    af[mt], bf[nt * 4 + c], acc[mt][nt], 0, 0, 0);
    }

    // Epilogue phase 1: acc -> LDS tile (bf16), C/D layout col=l&15,
    // row=(l>>4)*4+reg.
    __syncthreads();   // all A-frag reads complete before overwrite
#pragma unroll
    for (int mt = 0; mt < 4; ++mt) {
#pragma unroll
        for (int reg = 0; reg < 4; ++reg) {
            int row = wy * 64 + mt * 16 + (l >> 4) * 4 + reg;
#pragma unroll
            for (int nt = 0; nt < 4; ++nt)
                lA[row * LDA + wx * 64 + nt * 16 + lm] = f2b(acc[mt][nt][reg]);
        }
    }
    __syncthreads();

    // Epilogue phase 2: coalesced 16B/lane stores into [n][b][f] layout.
#pragma unroll
    for (int i = 0; i < 8; ++i) {
        int elem = i * 2048 + tid * 8;
        int row = elem >> 7, col = elem & 127;
        long R = rowBase + row;
        if (R < TOTROWS) {
            int b = (int)(R / NN);
            int n = (int)(R % NN);
            ushortx8 v = *(const ushortx8*)&lA[row * LDA + col];
            *(ushortx8*)(sup + ((size_t)n * BB + b) * DOUT + col) = v;
        }
    }
}

// ---------------------------------------------------------------------------
// CSR build
// ---------------------------------------------------------------------------
__global__ __launch_bounds__(256)
void k_hist(const int* __restrict__ rows, int* __restrict__ deg) {
    int e = blockIdx.x * 256 + threadIdx.x;
    if (e < EE) atomicAdd(&deg[rows[e]], 1);
}

#define CHUNK 1024
#define NCHUNK ((NN + CHUNK - 1) / CHUNK)   // 49

__global__ __launch_bounds__(256)
void k_scan_reduce(const int* __restrict__ deg, int* __restrict__ bsum) {
    __shared__ int sh[256];
    int t = threadIdx.x, blk = blockIdx.x;
    int base = blk * CHUNK + t * 4;
    int s = 0;
#pragma unroll
    for (int i = 0; i < 4; ++i) {
        int idx = base + i;
        if (idx < NN) s += deg[idx];
    }
    sh[t] = s;
    __syncthreads();
    for (int d = 128; d > 0; d >>= 1) {
        if (t < d) sh[t] += sh[t + d];
        __syncthreads();
    }
    if (t == 0) bsum[blk] = sh[0];
}

__global__ __launch_bounds__(64)
void k_scan_base(const int* __restrict__ bsum, int* __restrict__ bbase,
                 int* __restrict__ off) {
    int l = threadIdx.x;
    int orig = (l < NCHUNK) ? bsum[l] : 0;
    int v = orig;
    for (int d = 1; d < 64; d <<= 1) {
        int x = __shfl_up(v, d);
        if (l >= d) v += x;
    }
    if (l < NCHUNK) bbase[l] = v - orig;     // exclusive
    if (l == NCHUNK - 1) off[NN] = v;        // == E
}

__global__ __launch_bounds__(256)
void k_scan_chunk(const int* __restrict__ deg, const int* __restrict__ bbase,
                  int* __restrict__ off) {
    __shared__ int sh[256];
    int t = threadIdx.x;
    int blk = blockIdx.x;
    int base = blk * CHUNK + t * 4;
    int v[4];
    int tsum = 0;
#pragma unroll
    for (int i = 0; i < 4; ++i) {
        int idx = base + i;
        v[i] = (idx < NN) ? deg[idx] : 0;
        tsum += v[i];
    }
    sh[t] = tsum;
    __syncthreads();
    for (int d = 1; d < 256; d <<= 1) {
        int x = (t >= d) ? sh[t - d] : 0;
        __syncthreads();
        sh[t] += x;
        __syncthreads();
    }
    int run = sh[t] - tsum + bbase[blk];
#pragma unroll
    for (int i = 0; i < 4; ++i) {
        int idx = base + i;
        if (idx < NN) off[idx] = run;
        run += v[i];
    }
}

// Packed edge: .x = col, .y = float bits of val
__global__ __launch_bounds__(256)
void k_scatter(const int* __restrict__ rows, const int* __restrict__ cols,
               const void* __restrict__ valsv, const int* __restrict__ flags,
               const int* __restrict__ off, int* __restrict__ cur,
               int2* __restrict__ epk) {
    int e = blockIdx.x * 256 + threadIdx.x;
    if (e < EE) {
        int vf32 = flags[3];
        float v = vf32 ? ((const float*)valsv)[e] : b2f(((const u16*)valsv)[e]);
        int r = rows[e];
        int p = off[r] + atomicAdd(&cur[r], 1);
        epk[p] = make_int2(cols[e], __float_as_int(v));
    }
}

// ---------------------------------------------------------------------------
// K8: aggregation. One wave per node; lane covers (b = l>>4, f = (l&15)*8+t).
// out fp32. Edge loop unrolled x4, packed 8B edge loads, gathers batched.
// ---------------------------------------------------------------------------
__global__ __launch_bounds__(256)
void k_agg(const u16* __restrict__ sup, const int* __restrict__ off,
           const int2* __restrict__ epk, const void* __restrict__ biasv,
           const int* __restrict__ flags, float* __restrict__ out) {
    const int wid = threadIdx.x >> 6;
    const int l   = threadIdx.x & 63;
    const int n = blockIdx.x * 4 + wid;
    if (n >= NN) return;

    const int p0 = off[n];
    const int p1 = off[n + 1];

    float acc[8] = {0.f, 0.f, 0.f, 0.f, 0.f, 0.f, 0.f, 0.f};
    const int b  = l >> 4;
    const int f0 = (l & 15) * 8;
    const int lofs = l * 8;   // == b*128 + f0 in [n][b][f] layout

    int p = p0;
    for (; p + 4 <= p1; p += 4) {
        int2 e0 = epk[p],     e1 = epk[p + 1];
        int2 e2 = epk[p + 2], e3 = epk[p + 3];
        ushortx8 s0 = *(const ushortx8*)(sup + (size_t)e0.x * 512 + lofs);
        ushortx8 s1 = *(const ushortx8*)(sup + (size_t)e1.x * 512 + lofs);
        ushortx8 s2 = *(const ushortx8*)(sup + (size_t)e2.x * 512 + lofs);
        ushortx8 s3 = *(const ushortx8*)(sup + (size_t)e3.x * 512 + lofs);
        float v0 = __int_as_float(e0.y), v1 = __int_as_float(e1.y);
        float v2 = __int_as_float(e2.y), v3 = __int_as_float(e3.y);
#pragma unroll
        for (int t = 0; t < 8; ++t) acc[t] += v0 * b2f(s0[t]);
#pragma unroll
        for (int t = 0; t < 8; ++t) acc[t] += v1 * b2f(s1[t]);
#pragma unroll
        for (int t = 0; t < 8; ++t) acc[t] += v2 * b2f(s2[t]);
#pragma unroll
        for (int t = 0; t < 8; ++t) acc[t] += v3 * b2f(s3[t]);
    }
    for (; p < p1; ++p) {
        int2 e = epk[p];
        float v = __int_as_float(e.y);
        ushortx8 s = *(const ushortx8*)(sup + (size_t)e.x * 512 + lofs);
#pragma unroll
        for (int t = 0; t < 8; ++t) acc[t] += v * b2f(s[t]);
    }

    float bb[8];
    if (flags[2]) {
        float4 bv1 = *(const float4*)((const float*)biasv + f0);
        float4 bv2 = *(const float4*)((const float*)biasv + f0 + 4);
        bb[0] = bv1.x; bb[1] = bv1.y; bb[2] = bv1.z; bb[3] = bv1.w;
        bb[4] = bv2.x; bb[5] = bv2.y; bb[6] = bv2.z; bb[7] = bv2.w;
    } else {
        ushortx8 bv = *(const ushortx8*)((const u16*)biasv + f0);
#pragma unroll
        for (int t = 0; t < 8; ++t) bb[t] = b2f(bv[t]);
    }

    float r[8];
#pragma unroll
    for (int t = 0; t < 8; ++t) r[t] = fmaxf(acc[t] + bb[t], 0.f);

    float* op = out + ((size_t)b * NN + n) * DOUT + f0;
    *(float4*)op       = (float4){r[0], r[1], r[2], r[3]};
    *(float4*)(op + 4) = (float4){r[4], r[5], r[6], r[7]};
}

// ---------------------------------------------------------------------------
extern "C" void kernel_launch(void* const* d_in, const int* in_sizes, int n_in,
                              void* d_out, int out_size, void* d_ws, size_t ws_size,
                              hipStream_t stream) {
    const void* X    = d_in[0];
    const void* W    = d_in[1];
    const void* bias = d_in[2];
    const void* vals = d_in[3];
    const int* rows  = (const int*)d_in[4];
    const int* cols  = (const int*)d_in[5];
    float* out = (float*)d_out;

    char* base = (char*)d_ws;
    size_t o = 0;
    int* flags = (int*)(base + o); o += 64;
    int* deg = (int*)(base + o); o += (size_t)NN * 4;
    int* cur = (int*)(base + o); o += (size_t)NN * 4;    // deg+cur contiguous
    o = (o + 255) & ~(size_t)255;
    int* bsum  = (int*)(base + o); o += 64 * 4;
    int* bbase = (int*)(base + o); o += 64 * 4;
    o = (o + 255) & ~(size_t)255;
    u16* Wt = (u16*)(base + o); o += (size_t)DIN * DOUT * 2;
    o = (o + 255) & ~(size_t)255;
    int* off = (int*)(base + o); o += (size_t)(NN + 1) * 4;
    o = (o + 255) & ~(size_t)255;
    int2* epk = (int2*)(base + o); o += (size_t)EE * 8;
    o = (o + 255) & ~(size_t)255;
    u16* sup = (u16*)(base + o); o += (size_t)BB * NN * DOUT * 2;
    (void)ws_size;

    hipMemsetAsync(deg, 0, (size_t)2 * NN * 4, stream);  // deg + cur

    k_detect<<<1, 256, 0, stream>>>((const u16*)X, (const u16*)W,
                                    (const u16*)bias, (const u16*)vals,
                                    in_sizes[0], in_sizes[1], in_sizes[2],
                                    in_sizes[3], flags);
    k_prep<<<64, 256, 0, stream>>>(W, flags, Wt);
    k_gemm<<<(TOTROWS + 127) / 128, 256, 0, stream>>>(X, Wt, flags, sup);
    k_hist<<<(EE + 255) / 256, 256, 0, stream>>>(rows, deg);
    k_scan_reduce<<<NCHUNK, 256, 0, stream>>>(deg, bsum);
    k_scan_base<<<1, 64, 0, stream>>>(bsum, bbase, off);
    k_scan_chunk<<<NCHUNK, 256, 0, stream>>>(deg, bbase, off);
    k_scatter<<<(EE + 255) / 256, 256, 0, stream>>>(rows, cols, vals, flags,
                                                    off, cur, epk);
    k_agg<<<(NN + 3) / 4, 256, 0, stream>>>(sup, off, epk, bias, flags, out);
}